// Round 14
// baseline (99.242 us; speedup 1.0000x reference)
//
#include <hip/hip_runtime.h>
#include <math.h>

#define B_     2
#define N_     6890
#define NF_    2000
#define NFP_   2048     // padded triangles: 8 chunks x 256
#define NPT_   6912     // padded points: 27*256
#define OPP7_  7168     // padded opposite cloud: 7 chunks x 1024
#define TCG_   8        // tri chunks (256 tris each, 4 recs/lane)
#define OCG_   7        // opp chunks (1024 recs each, 16 recs/lane)
#define WTILE_ (4 * TCG_ * 27)            // 864 winding tiles (first)
#define NTILE_ (4 * (TCG_ + OCG_) * 27)   // 1620 total tiles = grid

typedef float v2f __attribute__((ext_vector_type(2)));
#define VFMA(a,b,c) __builtin_elementwise_fma((v2f)(a), (v2f)(b), (v2f)(c))
#define VMIN(a,b)   __builtin_elementwise_min((v2f)(a), (v2f)(b))

// rotate wave by 1: lane i <- lane (i+1)&63 (DPP wf_rol:1, pure VALU)
__device__ __forceinline__ float rotl1(float v) {
    return __int_as_float(__builtin_amdgcn_update_dpp(
        __float_as_int(v), __float_as_int(v), 0x134, 0xF, 0xF, false));
}

// ---------------------------------------------------------------------------
// atan2(y,x)/(2*pi): branchless octant reduction, single rcp, scale folded in.
// ---------------------------------------------------------------------------
__device__ __forceinline__ float atan2_o2pi(float y, float x) {
    float ax = __builtin_fabsf(x);
    float ay = __builtin_fabsf(y);
    float mx = fmaxf(ax, ay);
    float mn = fminf(ax, ay);
    bool  big = mn > 0.41421356f * mx;
    float num = big ? (mn - mx) : mn;
    float den = big ? (mn + mx) : mx;
    float t   = num * __builtin_amdgcn_rcpf(den);
    float z   = t * t;
    float p   = fmaf(fmaf(fmaf(1.2817932e-2f, z, -2.2087019e-2f), z,
                          3.1795514e-2f), z, -5.3051037e-2f);   // coeffs / 2pi
    float r   = fmaf(t, fmaf(z, p, 0.15915494309f), big ? 0.125f : 0.0f);
    r = (ay > ax)  ? 0.25f - r : r;
    r = (x < 0.0f) ? 0.5f  - r : r;
    return copysignf(r, y);
}

// wrap correction for angle addition (turn units): a+b = wrap(a+b) + corr
__device__ __forceinline__ float corr(float y1, float y2, float yc) {
    float c = (y1 > 0.f && y2 > 0.f && yc <= 0.f) ? 1.f : 0.f;
    c = (y1 < 0.f && y2 < 0.f && yc >= 0.f) ? -1.f : c;
    return c;
}

// packed triangle-pair constants (two records in v2f lanes)
struct TriPack {
    v2f Ax,Ay,Az,Bx,By,Bz,Cx,Cy,Cz,Sx,Sy,Sz,D0,Na,Nb,Nc,Qab,Qbc,Qca;
};

__device__ __forceinline__ TriPack packT(float4 a0, float4 a1, float4 a2,
                                         float4 a3, float4 a4,
                                         float4 b0, float4 b1, float4 b2,
                                         float4 b3, float4 b4) {
    TriPack T;
    T.Ax = (v2f){a0.x,b0.x}; T.Ay = (v2f){a0.y,b0.y}; T.Az = (v2f){a0.z,b0.z};
    T.Bx = (v2f){a0.w,b0.w}; T.By = (v2f){a1.x,b1.x}; T.Bz = (v2f){a1.y,b1.y};
    T.Cx = (v2f){a1.z,b1.z}; T.Cy = (v2f){a1.w,b1.w}; T.Cz = (v2f){a2.x,b2.x};
    T.Sx = (v2f){a2.y,b2.y}; T.Sy = (v2f){a2.z,b2.z}; T.Sz = (v2f){a2.w,b2.w};
    T.D0 = (v2f){a3.x,b3.x}; T.Na = (v2f){a3.y,b3.y}; T.Nb = (v2f){a3.z,b3.z};
    T.Nc = (v2f){a3.w,b3.w};
    T.Qab= (v2f){a4.x,b4.x}; T.Qbc= (v2f){a4.y,b4.y}; T.Qca= (v2f){a4.z,b4.z};
    return T;
}

// Van Oosterom-Strackee det/denom for two triangles (v2f lanes) vs point
__device__ __forceinline__ void chain(const TriPack& T, v2f px, v2f py, v2f pz,
                                      v2f sv, v2f& yo, v2f& xo) {
    v2f dAp = VFMA(T.Ax, px, VFMA(T.Ay, py, T.Az * pz));
    v2f dBp = VFMA(T.Bx, px, VFMA(T.By, py, T.Bz * pz));
    v2f dCp = VFMA(T.Cx, px, VFMA(T.Cy, py, T.Cz * pz));
    v2f det = VFMA(T.Sx, px, VFMA(T.Sy, py, VFMA(T.Sz, pz, T.D0)));
    v2f la2 = VFMA((v2f)(-2.f), dAp, T.Na + sv);
    v2f lb2 = VFMA((v2f)(-2.f), dBp, T.Nb + sv);
    v2f lc2 = VFMA((v2f)(-2.f), dCp, T.Nc + sv);
    v2f la, lb, lc;
    la.x = __builtin_amdgcn_sqrtf(fmaxf(la2.x, 0.f));
    la.y = __builtin_amdgcn_sqrtf(fmaxf(la2.y, 0.f));
    lb.x = __builtin_amdgcn_sqrtf(fmaxf(lb2.x, 0.f));
    lb.y = __builtin_amdgcn_sqrtf(fmaxf(lb2.y, 0.f));
    lc.x = __builtin_amdgcn_sqrtf(fmaxf(lc2.x, 0.f));
    lc.y = __builtin_amdgcn_sqrtf(fmaxf(lc2.y, 0.f));
    v2f dab = (T.Qab + sv) - (dAp + dBp);
    v2f dbc = (T.Qbc + sv) - (dBp + dCp);
    v2f dca = (T.Qca + sv) - (dCp + dAp);
    xo = VFMA(VFMA(la, lb, dab), lc, VFMA(dbc, la, dca * lb));
    yo = det;
}

// ---------------------------------------------------------------------------
// prep (layouts unchanged):
//  pw[b][n] = (x,y,z,|p|^2)        pad zeros              [B][NPT_]
//  st[b][n] = (-2x,-2y,-2z,|o|^2)  pad (0,0,0,1e30)       [B][OPP7_]
//  tbl[b][f][20] = [A,B,C, -S, det0, na,nb,nc, qab,qbc,qca, 0]
// ---------------------------------------------------------------------------
__global__ void prep_kernel(const float* __restrict__ v1, const float* __restrict__ v2,
                            const int* __restrict__ faces,
                            float4* __restrict__ pw1, float4* __restrict__ pw2,
                            float4* __restrict__ st1, float4* __restrict__ st2,
                            float* __restrict__ tbl1, float* __restrict__ tbl2) {
    int tid = blockIdx.x * 256 + threadIdx.x;

    if (tid < B_ * NPT_) {
        int b = tid / NPT_, n = tid - b * NPT_;
        float4 q1 = make_float4(0.f, 0.f, 0.f, 0.f), q2 = q1;
        if (n < N_) {
            float x1 = v1[(b*N_+n)*3+0], y1 = v1[(b*N_+n)*3+1], z1 = v1[(b*N_+n)*3+2];
            float x2 = v2[(b*N_+n)*3+0], y2 = v2[(b*N_+n)*3+1], z2 = v2[(b*N_+n)*3+2];
            q1 = make_float4(x1, y1, z1, fmaf(x1,x1, fmaf(y1,y1, z1*z1)));
            q2 = make_float4(x2, y2, z2, fmaf(x2,x2, fmaf(y2,y2, z2*z2)));
        }
        pw1[tid] = q1; pw2[tid] = q2;
    }

    if (tid < B_ * OPP7_) {
        int b = tid / OPP7_, n = tid - b * OPP7_;
        float4 q1 = make_float4(0.f, 0.f, 0.f, 1e30f), q2 = q1;
        if (n < N_) {
            float x1 = v1[(b*N_+n)*3+0], y1 = v1[(b*N_+n)*3+1], z1 = v1[(b*N_+n)*3+2];
            float x2 = v2[(b*N_+n)*3+0], y2 = v2[(b*N_+n)*3+1], z2 = v2[(b*N_+n)*3+2];
            q1 = make_float4(-2.f*x1, -2.f*y1, -2.f*z1, fmaf(x1,x1, fmaf(y1,y1, z1*z1)));
            q2 = make_float4(-2.f*x2, -2.f*y2, -2.f*z2, fmaf(x2,x2, fmaf(y2,y2, z2*z2)));
        }
        st1[tid] = q1; st2[tid] = q2;
    }

    if (tid < 2 * B_ * NFP_) {
        int src = tid >> 12;
        int rr  = tid & (B_ * NFP_ - 1);
        int b   = rr >> 11;
        int f   = rr & (NFP_ - 1);
        const float* V = src ? v2 : v1;
        float Ax=1.f,Ay=1.f,Az=1.f,Bx=1.f,By=1.f,Bz=1.f,Cx=1.f,Cy=1.f,Cz=1.f;
        if (f < NF_) {
            int i0 = faces[f*3+0], i1 = faces[f*3+1], i2 = faces[f*3+2];
            Ax=V[(b*N_+i0)*3+0]; Ay=V[(b*N_+i0)*3+1]; Az=V[(b*N_+i0)*3+2];
            Bx=V[(b*N_+i1)*3+0]; By=V[(b*N_+i1)*3+1]; Bz=V[(b*N_+i1)*3+2];
            Cx=V[(b*N_+i2)*3+0]; Cy=V[(b*N_+i2)*3+1]; Cz=V[(b*N_+i2)*3+2];
        }
        float Sx = (Ay*Bz - Az*By) + (By*Cz - Bz*Cy) + (Cy*Az - Cz*Ay);
        float Sy = (Az*Bx - Ax*Bz) + (Bz*Cx - Bx*Cz) + (Cz*Ax - Cx*Az);
        float Sz = (Ax*By - Ay*Bx) + (Bx*Cy - By*Cx) + (Cx*Ay - Cy*Ax);
        float det0 = Ax*(By*Cz - Bz*Cy) + Ay*(Bz*Cx - Bx*Cz) + Az*(Bx*Cy - By*Cx);
        float na = Ax*Ax+Ay*Ay+Az*Az, nb = Bx*Bx+By*By+Bz*Bz, nc = Cx*Cx+Cy*Cy+Cz*Cz;
        float qab = Ax*Bx+Ay*By+Az*Bz, qbc = Bx*Cx+By*Cy+Bz*Cz, qca = Cx*Ax+Cy*Ay+Cz*Az;
        float* o = (src ? tbl2 : tbl1) + ((b << 11) + f) * 20;
        o[0]=Ax;  o[1]=Ay;  o[2]=Az;  o[3]=Bx;  o[4]=By;  o[5]=Bz;
        o[6]=Cx;  o[7]=Cy;  o[8]=Cz;  o[9]=-Sx; o[10]=-Sy; o[11]=-Sz;
        o[12]=det0; o[13]=na; o[14]=nb; o[15]=nc;
        o[16]=qab;  o[17]=qbc; o[18]=qca; o[19]=0.f;
    }
}

// ---------------------------------------------------------------------------
// mega: one tile per block, grid = 1620. __launch_bounds__(256, 3) raises the
// VGPR cap to ~170 so the loop-invariant records ACTUALLY live in registers
// (previous builds were pinned at 56-64 VGPR -> compiler re-loaded records
// inside the hot loop). Winding: 4 recs/lane, complex-product fusion
// (1 atan2 / 4 tris). Rowmin: 16 recs/lane packed into 8 v2f pk-fma chains.
// ---------------------------------------------------------------------------
__global__ __launch_bounds__(256, 3) void mega_kernel(
        const float4* __restrict__ pw1, const float4* __restrict__ pw2,
        const float* __restrict__ tbl1, const float* __restrict__ tbl2,
        const float4* __restrict__ st1, const float4* __restrict__ st2,
        float* __restrict__ part, float* __restrict__ rmp) {
    __shared__ float4 ptsd[512];    // 4 waves x (64 pts duplicated) = 8 KB
    int t = threadIdx.x, wid = t >> 6, lane = t & 63;
    int pbase = (wid << 7) + lane;  // doubled-slice base
    int tile = blockIdx.x;

    if (tile < WTILE_) {
        // ---------------- winding ----------------
        int pgrp = tile % 27;
        int r    = tile / 27;                 // [0, 32)
        int cg   = r & 7, db = r >> 3;
        int b = db & 1, dir = db >> 1;

        const float4* pw  = dir ? pw2 : pw1;
        const float*  tbl = dir ? tbl1 : tbl2;

        float4 P0 = pw[b * NPT_ + pgrp * 256 + t];
        ptsd[pbase]      = P0;
        ptsd[pbase + 64] = P0;

        const float4* rp0 = (const float4*)(tbl + (size_t)(b*NFP_ + cg*256 +   0 + lane)*20);
        const float4* rp1 = (const float4*)(tbl + (size_t)(b*NFP_ + cg*256 +  64 + lane)*20);
        const float4* rp2 = (const float4*)(tbl + (size_t)(b*NFP_ + cg*256 + 128 + lane)*20);
        const float4* rp3 = (const float4*)(tbl + (size_t)(b*NFP_ + cg*256 + 192 + lane)*20);
        TriPack TA = packT(rp0[0],rp0[1],rp0[2],rp0[3],rp0[4],
                           rp1[0],rp1[1],rp1[2],rp1[3],rp1[4]);
        TriPack TB = packT(rp2[0],rp2[1],rp2[2],rp2[3],rp2[4],
                           rp3[0],rp3[1],rp3[2],rp3[3],rp3[4]);

        const float4* mypts = ptsd + pbase;
        float acc = 0.f;
        #pragma unroll 2
        for (int k = 0; k < 64; ++k) {
            float4 P = mypts[k];              // base + immediate offset
            v2f px = P.x, py = P.y, pz = P.z, sv = P.w;
            v2f yA, xA, yB, xB;
            chain(TA, px, py, pz, sv, yA, xA);
            chain(TB, px, py, pz, sv, yB, xB);
            // level-1 complex combine (pk): pairs (t0*t2) and (t1*t3)
            v2f yP = VFMA(yA, xB, yB * xA);
            v2f xP = VFMA(-yA, yB, xA * xB);
            float c01 = corr(yA.x, yB.x, yP.x) + corr(yA.y, yB.y, yP.y);
            // level-2 scalar combine
            float yT = fmaf(yP.x, xP.y, yP.y * xP.x);
            float xT = fmaf(-yP.x, yP.y, xP.x * xP.y);
            float c2 = corr(yP.x, yP.y, yT);
            acc = rotl1(acc + (atan2_o2pi(yT, xT) + (c01 + c2)));
        }
        part[(db*TCG_ + cg)*NPT_ + pgrp*256 + t] = acc;
    } else {
        // ---------------- rowmin (pk-packed distance chains) ----------------
        int rb   = tile - WTILE_;             // [0, 756)
        int pgrp = rb % 27;
        int r    = rb / 27;                   // [0, 28)
        int ocg  = r % OCG_, db = r / OCG_;
        int b = db & 1, dir = db >> 1;

        const float4* pw = dir ? pw2 : pw1;
        const float4* st = dir ? st1 : st2;

        float4 P0 = pw[b * NPT_ + pgrp * 256 + t];
        ptsd[pbase]      = P0;
        ptsd[pbase + 64] = P0;

        const float4* qb = st + b * OPP7_ + ocg * 1024;
        // load 16 records, pack pairs (j, j+8) component-wise into v2f
#define LQP(j)                                                               \
        float4 qa##j = qb[j*64 + lane];                                      \
        float4 qc##j = qb[(j+8)*64 + lane];                                  \
        v2f Qx##j = {qa##j.x, qc##j.x}, Qy##j = {qa##j.y, qc##j.y},          \
            Qz##j = {qa##j.z, qc##j.z}, Qw##j = {qa##j.w, qc##j.w};
        LQP(0) LQP(1) LQP(2) LQP(3) LQP(4) LQP(5) LQP(6) LQP(7)
#undef LQP

        const float4* mypts = ptsd + pbase;
        float m = 3.4e38f;
        #pragma unroll 2
        for (int k = 0; k < 64; ++k) {
            float4 P = mypts[k];
            float s = P.w;
            v2f px = P.x, py = P.y, pz = P.z;
#define DDP(j) v2f D##j = VFMA(Qx##j, px, VFMA(Qy##j, py, VFMA(Qz##j, pz, Qw##j)));
            DDP(0) DDP(1) DDP(2) DDP(3) DDP(4) DDP(5) DDP(6) DDP(7)
#undef DDP
            v2f e0 = VMIN(D0, D1), e1 = VMIN(D2, D3);
            v2f e2 = VMIN(D4, D5), e3 = VMIN(D6, D7);
            v2f f0 = VMIN(e0, e1), f1 = VMIN(e2, e3);
            v2f g  = VMIN(f0, f1);
            float h = fminf(g.x, g.y);
            m = rotl1(fminf(m, h + s));       // |p|^2 hoisted out of fmas
        }
        rmp[(db*OCG_ + ocg)*NPT_ + pgrp*256 + t] = m;
    }
}

// ---------------------------------------------------------------------------
// fold: per (db, 256-point group): sum 8 winding partials, min 7 rowmin
// partials, block-reduce masked stats -> pstat[db*27+pg].
// ---------------------------------------------------------------------------
__global__ __launch_bounds__(256) void fold_kernel(
        const float* __restrict__ part, const float* __restrict__ rmp,
        float4* __restrict__ pstat) {
    int pg = blockIdx.x % 27, db = blockIdx.x / 27;
    int t = threadIdx.x, n = pg * 256 + t;

    float ws = 0.f;
    #pragma unroll
    for (int g = 0; g < TCG_; ++g) ws += part[(db*TCG_ + g)*NPT_ + n];
    float rv = 3.4e38f;
    #pragma unroll
    for (int g = 0; g < OCG_; ++g) rv = fminf(rv, rmp[(db*OCG_ + g)*NPT_ + n]);

    bool valid = n < N_;
    float d = sqrtf(rv);
    bool msk = valid && (ws >= 0.99f);
    float v_min = valid ? d : 3.4e38f;
    float v_max = msk ? d : -3.4e38f;
    float v_sum = msk ? d : 0.f;
    float v_cnt = msk ? 1.f : 0.f;

    #pragma unroll
    for (int off = 32; off; off >>= 1) {
        v_min = fminf(v_min, __shfl_down(v_min, off, 64));
        v_max = fmaxf(v_max, __shfl_down(v_max, off, 64));
        v_sum += __shfl_down(v_sum, off, 64);
        v_cnt += __shfl_down(v_cnt, off, 64);
    }
    __shared__ float4 sred[4];
    int wid = t >> 6, lane = t & 63;
    if (lane == 0) sred[wid] = make_float4(v_min, v_max, v_sum, v_cnt);
    __syncthreads();
    if (t == 0) {
        float4 a = sred[0], bb = sred[1], c = sred[2], dd = sred[3];
        pstat[db*27 + pg] = make_float4(
            fminf(fminf(a.x, bb.x), fminf(c.x, dd.x)),
            fmaxf(fmaxf(a.y, bb.y), fmaxf(c.y, dd.y)),
            (a.z + bb.z) + (c.z + dd.z),
            (a.w + bb.w) + (c.w + dd.w));
    }
}

// ---------------------------------------------------------------------------
// final: 1 block, wave w reduces db=w's 27 group stats; thread 0 writes [5][B].
// ---------------------------------------------------------------------------
__global__ void final_kernel(const float4* __restrict__ pstat, float* __restrict__ out) {
    int t = threadIdx.x, wid = t >> 6, lane = t & 63;    // wid = db
    float4 v = make_float4(3.4e38f, -3.4e38f, 0.f, 0.f);
    if (lane < 27) v = pstat[wid*27 + lane];
    #pragma unroll
    for (int off = 32; off; off >>= 1) {
        v.x = fminf(v.x, __shfl_down(v.x, off, 64));
        v.y = fmaxf(v.y, __shfl_down(v.y, off, 64));
        v.z += __shfl_down(v.z, off, 64);
        v.w += __shfl_down(v.w, off, 64);
    }
    __shared__ float4 res[4];
    if (lane == 0) res[wid] = v;
    __syncthreads();
    if (t == 0) {
        #pragma unroll
        for (int b = 0; b < B_; ++b) {
            float4 s1 = res[b], s2 = res[2 + b];
            out[0 + b] = s1.x;
            out[2 + b] = (s1.w > 0.f) ? s1.y : 0.f;
            out[4 + b] = (s1.w > 0.f) ? (s1.z / s1.w) : 0.f;
            out[6 + b] = (s2.w > 0.f) ? s2.y : 0.f;
            out[8 + b] = (s2.w > 0.f) ? (s2.z / s2.w) : 0.f;
        }
    }
}

extern "C" void kernel_launch(void* const* d_in, const int* in_sizes, int n_in,
                              void* d_out, int out_size, void* d_ws, size_t ws_size,
                              hipStream_t stream) {
    const float* v1    = (const float*)d_in[0];
    const float* v2    = (const float*)d_in[1];
    const int*   faces = (const int*)d_in[2];

    float4* f4 = (float4*)d_ws;
    float4* pw1   = f4;                         // B*NPT_  = 13824 f4
    float4* pw2   = pw1 + B_ * NPT_;
    float4* st1   = pw2 + B_ * NPT_;            // B*OPP7_ = 14336 f4
    float4* st2   = st1 + B_ * OPP7_;
    float4* pstat = st2 + B_ * OPP7_;           // 108 f4
    float*  tbl1  = (float*)(pstat + 128);      // B*NFP_*20 = 81920 f
    float*  tbl2  = tbl1 + B_ * NFP_ * 20;
    float*  part  = tbl2 + B_ * NFP_ * 20;      // 4*TCG_*NPT_ = 221184 f
    float*  rmp   = part + 4 * TCG_ * NPT_;     // 4*OCG_*NPT_ = 193536 f
                                                // total ~3.3 MB

    float* out = (float*)d_out;

    prep_kernel<<<(B_ * OPP7_ + 255) / 256, 256, 0, stream>>>(
        v1, v2, faces, pw1, pw2, st1, st2, tbl1, tbl2);

    mega_kernel<<<NTILE_, 256, 0, stream>>>(
        pw1, pw2, tbl1, tbl2, st1, st2, part, rmp);

    fold_kernel<<<4 * 27, 256, 0, stream>>>(part, rmp, pstat);

    final_kernel<<<1, 256, 0, stream>>>(pstat, out);
}

// Round 15
// 91.334 us; speedup vs baseline: 1.0866x; 1.0866x over previous
//
#include <hip/hip_runtime.h>
#include <math.h>

#define B_     2
#define N_     6890
#define NF_    2000
#define NFP_   2048     // padded triangles: 8 chunks x 256
#define NPT_   6912     // padded points: 27*256
#define OPP7_  7168     // padded opposite cloud: 7 chunks x 1024
#define TCG_   8        // tri chunks (256 tris each, 4 recs/lane)
#define OCG_   7        // opp chunks (1024 recs each, 16 recs/lane)
#define WTILE_ (4 * TCG_ * 27)            // 864 winding tiles (first)
#define NTILE_ (4 * (TCG_ + OCG_) * 27)   // 1620 total tiles = grid

typedef float v2f __attribute__((ext_vector_type(2)));
#define VFMA(a,b,c) __builtin_elementwise_fma((v2f)(a), (v2f)(b), (v2f)(c))

// rotate wave by 1: lane i <- lane (i+1)&63 (DPP wf_rol:1, pure VALU)
__device__ __forceinline__ float rotl1(float v) {
    return __int_as_float(__builtin_amdgcn_update_dpp(
        __float_as_int(v), __float_as_int(v), 0x134, 0xF, 0xF, false));
}

// ---------------------------------------------------------------------------
// atan2(y,x)/(2*pi): branchless octant reduction, single rcp, scale folded in.
// ---------------------------------------------------------------------------
__device__ __forceinline__ float atan2_o2pi(float y, float x) {
    float ax = __builtin_fabsf(x);
    float ay = __builtin_fabsf(y);
    float mx = fmaxf(ax, ay);
    float mn = fminf(ax, ay);
    bool  big = mn > 0.41421356f * mx;
    float num = big ? (mn - mx) : mn;
    float den = big ? (mn + mx) : mx;
    float t   = num * __builtin_amdgcn_rcpf(den);
    float z   = t * t;
    float p   = fmaf(fmaf(fmaf(1.2817932e-2f, z, -2.2087019e-2f), z,
                          3.1795514e-2f), z, -5.3051037e-2f);   // coeffs / 2pi
    float r   = fmaf(t, fmaf(z, p, 0.15915494309f), big ? 0.125f : 0.0f);
    r = (ay > ax)  ? 0.25f - r : r;
    r = (x < 0.0f) ? 0.5f  - r : r;
    return copysignf(r, y);
}

// wrap correction for angle addition (turn units): a+b = wrap(a+b) + corr
__device__ __forceinline__ float corr(float y1, float y2, float yc) {
    float c = (y1 > 0.f && y2 > 0.f && yc <= 0.f) ? 1.f : 0.f;
    c = (y1 < 0.f && y2 < 0.f && yc >= 0.f) ? -1.f : c;
    return c;
}

// packed triangle-pair constants (two records in v2f lanes)
struct TriPack {
    v2f Ax,Ay,Az,Bx,By,Bz,Cx,Cy,Cz,Sx,Sy,Sz,D0,Na,Nb,Nc,Qab,Qbc,Qca;
};

// pin all 19 v2f members into VGPRs as loop-carried values: the empty asm
// REDEFINES them each iteration, so the compiler cannot re-load them from
// memory inside the loop (r13/r14 builds allocated only 56-64 VGPR, provably
// re-loading the 76-float record state every iteration).
#define PIN19(T)                                                             \
    asm volatile("" : "+v"(T.Ax), "+v"(T.Ay), "+v"(T.Az), "+v"(T.Bx),        \
                      "+v"(T.By), "+v"(T.Bz), "+v"(T.Cx), "+v"(T.Cy),        \
                      "+v"(T.Cz), "+v"(T.Sx), "+v"(T.Sy), "+v"(T.Sz),        \
                      "+v"(T.D0), "+v"(T.Na), "+v"(T.Nb), "+v"(T.Nc),        \
                      "+v"(T.Qab), "+v"(T.Qbc), "+v"(T.Qca))

__device__ __forceinline__ TriPack packT(float4 a0, float4 a1, float4 a2,
                                         float4 a3, float4 a4,
                                         float4 b0, float4 b1, float4 b2,
                                         float4 b3, float4 b4) {
    TriPack T;
    T.Ax = (v2f){a0.x,b0.x}; T.Ay = (v2f){a0.y,b0.y}; T.Az = (v2f){a0.z,b0.z};
    T.Bx = (v2f){a0.w,b0.w}; T.By = (v2f){a1.x,b1.x}; T.Bz = (v2f){a1.y,b1.y};
    T.Cx = (v2f){a1.z,b1.z}; T.Cy = (v2f){a1.w,b1.w}; T.Cz = (v2f){a2.x,b2.x};
    T.Sx = (v2f){a2.y,b2.y}; T.Sy = (v2f){a2.z,b2.z}; T.Sz = (v2f){a2.w,b2.w};
    T.D0 = (v2f){a3.x,b3.x}; T.Na = (v2f){a3.y,b3.y}; T.Nb = (v2f){a3.z,b3.z};
    T.Nc = (v2f){a3.w,b3.w};
    T.Qab= (v2f){a4.x,b4.x}; T.Qbc= (v2f){a4.y,b4.y}; T.Qca= (v2f){a4.z,b4.z};
    return T;
}

// Van Oosterom-Strackee det/denom for two triangles (v2f lanes) vs point
__device__ __forceinline__ void chain(const TriPack& T, v2f px, v2f py, v2f pz,
                                      v2f sv, v2f& yo, v2f& xo) {
    v2f dAp = VFMA(T.Ax, px, VFMA(T.Ay, py, T.Az * pz));
    v2f dBp = VFMA(T.Bx, px, VFMA(T.By, py, T.Bz * pz));
    v2f dCp = VFMA(T.Cx, px, VFMA(T.Cy, py, T.Cz * pz));
    v2f det = VFMA(T.Sx, px, VFMA(T.Sy, py, VFMA(T.Sz, pz, T.D0)));
    v2f la2 = VFMA((v2f)(-2.f), dAp, T.Na + sv);
    v2f lb2 = VFMA((v2f)(-2.f), dBp, T.Nb + sv);
    v2f lc2 = VFMA((v2f)(-2.f), dCp, T.Nc + sv);
    v2f la, lb, lc;
    la.x = __builtin_amdgcn_sqrtf(fmaxf(la2.x, 0.f));
    la.y = __builtin_amdgcn_sqrtf(fmaxf(la2.y, 0.f));
    lb.x = __builtin_amdgcn_sqrtf(fmaxf(lb2.x, 0.f));
    lb.y = __builtin_amdgcn_sqrtf(fmaxf(lb2.y, 0.f));
    lc.x = __builtin_amdgcn_sqrtf(fmaxf(lc2.x, 0.f));
    lc.y = __builtin_amdgcn_sqrtf(fmaxf(lc2.y, 0.f));
    v2f dab = (T.Qab + sv) - (dAp + dBp);
    v2f dbc = (T.Qbc + sv) - (dBp + dCp);
    v2f dca = (T.Qca + sv) - (dCp + dAp);
    xo = VFMA(VFMA(la, lb, dab), lc, VFMA(dbc, la, dca * lb));
    yo = det;
}

// ---------------------------------------------------------------------------
// prep (layouts unchanged):
//  pw[b][n] = (x,y,z,|p|^2)        pad zeros              [B][NPT_]
//  st[b][n] = (-2x,-2y,-2z,|o|^2)  pad (0,0,0,1e30)       [B][OPP7_]
//  tbl[b][f][20] = [A,B,C, -S, det0, na,nb,nc, qab,qbc,qca, 0]
// ---------------------------------------------------------------------------
__global__ void prep_kernel(const float* __restrict__ v1, const float* __restrict__ v2,
                            const int* __restrict__ faces,
                            float4* __restrict__ pw1, float4* __restrict__ pw2,
                            float4* __restrict__ st1, float4* __restrict__ st2,
                            float* __restrict__ tbl1, float* __restrict__ tbl2) {
    int tid = blockIdx.x * 256 + threadIdx.x;

    if (tid < B_ * NPT_) {
        int b = tid / NPT_, n = tid - b * NPT_;
        float4 q1 = make_float4(0.f, 0.f, 0.f, 0.f), q2 = q1;
        if (n < N_) {
            float x1 = v1[(b*N_+n)*3+0], y1 = v1[(b*N_+n)*3+1], z1 = v1[(b*N_+n)*3+2];
            float x2 = v2[(b*N_+n)*3+0], y2 = v2[(b*N_+n)*3+1], z2 = v2[(b*N_+n)*3+2];
            q1 = make_float4(x1, y1, z1, fmaf(x1,x1, fmaf(y1,y1, z1*z1)));
            q2 = make_float4(x2, y2, z2, fmaf(x2,x2, fmaf(y2,y2, z2*z2)));
        }
        pw1[tid] = q1; pw2[tid] = q2;
    }

    if (tid < B_ * OPP7_) {
        int b = tid / OPP7_, n = tid - b * OPP7_;
        float4 q1 = make_float4(0.f, 0.f, 0.f, 1e30f), q2 = q1;
        if (n < N_) {
            float x1 = v1[(b*N_+n)*3+0], y1 = v1[(b*N_+n)*3+1], z1 = v1[(b*N_+n)*3+2];
            float x2 = v2[(b*N_+n)*3+0], y2 = v2[(b*N_+n)*3+1], z2 = v2[(b*N_+n)*3+2];
            q1 = make_float4(-2.f*x1, -2.f*y1, -2.f*z1, fmaf(x1,x1, fmaf(y1,y1, z1*z1)));
            q2 = make_float4(-2.f*x2, -2.f*y2, -2.f*z2, fmaf(x2,x2, fmaf(y2,y2, z2*z2)));
        }
        st1[tid] = q1; st2[tid] = q2;
    }

    if (tid < 2 * B_ * NFP_) {
        int src = tid >> 12;
        int rr  = tid & (B_ * NFP_ - 1);
        int b   = rr >> 11;
        int f   = rr & (NFP_ - 1);
        const float* V = src ? v2 : v1;
        float Ax=1.f,Ay=1.f,Az=1.f,Bx=1.f,By=1.f,Bz=1.f,Cx=1.f,Cy=1.f,Cz=1.f;
        if (f < NF_) {
            int i0 = faces[f*3+0], i1 = faces[f*3+1], i2 = faces[f*3+2];
            Ax=V[(b*N_+i0)*3+0]; Ay=V[(b*N_+i0)*3+1]; Az=V[(b*N_+i0)*3+2];
            Bx=V[(b*N_+i1)*3+0]; By=V[(b*N_+i1)*3+1]; Bz=V[(b*N_+i1)*3+2];
            Cx=V[(b*N_+i2)*3+0]; Cy=V[(b*N_+i2)*3+1]; Cz=V[(b*N_+i2)*3+2];
        }
        float Sx = (Ay*Bz - Az*By) + (By*Cz - Bz*Cy) + (Cy*Az - Cz*Ay);
        float Sy = (Az*Bx - Ax*Bz) + (Bz*Cx - Bx*Cz) + (Cz*Ax - Cx*Az);
        float Sz = (Ax*By - Ay*Bx) + (Bx*Cy - By*Cx) + (Cx*Ay - Cy*Ax);
        float det0 = Ax*(By*Cz - Bz*Cy) + Ay*(Bz*Cx - Bx*Cz) + Az*(Bx*Cy - By*Cx);
        float na = Ax*Ax+Ay*Ay+Az*Az, nb = Bx*Bx+By*By+Bz*Bz, nc = Cx*Cx+Cy*Cy+Cz*Cz;
        float qab = Ax*Bx+Ay*By+Az*Bz, qbc = Bx*Cx+By*Cy+Bz*Cz, qca = Cx*Ax+Cy*Ay+Cz*Az;
        float* o = (src ? tbl2 : tbl1) + ((b << 11) + f) * 20;
        o[0]=Ax;  o[1]=Ay;  o[2]=Az;  o[3]=Bx;  o[4]=By;  o[5]=Bz;
        o[6]=Cx;  o[7]=Cy;  o[8]=Cz;  o[9]=-Sx; o[10]=-Sy; o[11]=-Sz;
        o[12]=det0; o[13]=na; o[14]=nb; o[15]=nc;
        o[16]=qab;  o[17]=qbc; o[18]=qca; o[19]=0.f;
    }
}

// ---------------------------------------------------------------------------
// mega: one tile per block, grid = 1620 (winding tiles 0..863, rowmin
// 864..1619). No barriers. Winding: 4 recs/lane, complex-product fusion
// (1 atan2 / 4 tris), records PINNED in VGPRs. Rowmin: 16 recs/lane as 32
// v2f, pinned likewise.
// ---------------------------------------------------------------------------
__global__ __launch_bounds__(256) void mega_kernel(
        const float4* __restrict__ pw1, const float4* __restrict__ pw2,
        const float* __restrict__ tbl1, const float* __restrict__ tbl2,
        const float4* __restrict__ st1, const float4* __restrict__ st2,
        float* __restrict__ part, float* __restrict__ rmp) {
    __shared__ float4 ptsd[512];    // 4 waves x (64 pts duplicated) = 8 KB
    int t = threadIdx.x, wid = t >> 6, lane = t & 63;
    int pbase = (wid << 7) + lane;  // doubled-slice base
    int tile = blockIdx.x;

    if (tile < WTILE_) {
        // ---------------- winding ----------------
        int pgrp = tile % 27;
        int r    = tile / 27;                 // [0, 32)
        int cg   = r & 7, db = r >> 3;
        int b = db & 1, dir = db >> 1;

        const float4* pw  = dir ? pw2 : pw1;
        const float*  tbl = dir ? tbl1 : tbl2;

        float4 P0 = pw[b * NPT_ + pgrp * 256 + t];
        ptsd[pbase]      = P0;
        ptsd[pbase + 64] = P0;

        const float4* rp0 = (const float4*)(tbl + (size_t)(b*NFP_ + cg*256 +   0 + lane)*20);
        const float4* rp1 = (const float4*)(tbl + (size_t)(b*NFP_ + cg*256 +  64 + lane)*20);
        const float4* rp2 = (const float4*)(tbl + (size_t)(b*NFP_ + cg*256 + 128 + lane)*20);
        const float4* rp3 = (const float4*)(tbl + (size_t)(b*NFP_ + cg*256 + 192 + lane)*20);
        TriPack TA = packT(rp0[0],rp0[1],rp0[2],rp0[3],rp0[4],
                           rp1[0],rp1[1],rp1[2],rp1[3],rp1[4]);
        TriPack TB = packT(rp2[0],rp2[1],rp2[2],rp2[3],rp2[4],
                           rp3[0],rp3[1],rp3[2],rp3[3],rp3[4]);

        const float4* mypts = ptsd + pbase;
        float acc = 0.f;
        #pragma unroll 2
        for (int k = 0; k < 64; ++k) {
            float4 P = mypts[k];              // base + immediate offset
            v2f px = P.x, py = P.y, pz = P.z, sv = P.w;
            v2f yA, xA, yB, xB;
            chain(TA, px, py, pz, sv, yA, xA);
            chain(TB, px, py, pz, sv, yB, xB);
            // level-1 complex combine (pk): pairs (t0*t2) and (t1*t3)
            v2f yP = VFMA(yA, xB, yB * xA);
            v2f xP = VFMA(-yA, yB, xA * xB);
            float c01 = corr(yA.x, yB.x, yP.x) + corr(yA.y, yB.y, yP.y);
            // level-2 scalar combine
            float yT = fmaf(yP.x, xP.y, yP.y * xP.x);
            float xT = fmaf(-yP.x, yP.y, xP.x * xP.y);
            float c2 = corr(yP.x, yP.y, yT);
            acc = rotl1(acc + (atan2_o2pi(yT, xT) + (c01 + c2)));
            PIN19(TA);                        // force records loop-carried
            PIN19(TB);
        }
        part[(db*TCG_ + cg)*NPT_ + pgrp*256 + t] = acc;
    } else {
        // ---------------- rowmin ----------------
        int rb   = tile - WTILE_;             // [0, 756)
        int pgrp = rb % 27;
        int r    = rb / 27;                   // [0, 28)
        int ocg  = r % OCG_, db = r / OCG_;
        int b = db & 1, dir = db >> 1;

        const float4* pw = dir ? pw2 : pw1;
        const float4* st = dir ? st1 : st2;

        float4 P0 = pw[b * NPT_ + pgrp * 256 + t];
        ptsd[pbase]      = P0;
        ptsd[pbase + 64] = P0;

        const float4* qbase = st + b * OPP7_ + ocg * 1024;
        // 16 records as 32 v2f (xy | zw) so they can be pinned uniformly
#define LQ(j) float4 _q##j = qbase[j*64 + lane];                             \
              v2f qa##j = {_q##j.x, _q##j.y};                                \
              v2f qc##j = {_q##j.z, _q##j.w};
        LQ(0) LQ(1) LQ(2) LQ(3) LQ(4) LQ(5) LQ(6) LQ(7)
        LQ(8) LQ(9) LQ(10) LQ(11) LQ(12) LQ(13) LQ(14) LQ(15)
#undef LQ

        const float4* mypts = ptsd + pbase;
        float m = 3.4e38f;
        #pragma unroll 2
        for (int k = 0; k < 64; ++k) {
            float4 P = mypts[k];
            float s = P.w;
#define DD(j) float d##j = fmaf(qa##j.x, P.x, fmaf(qa##j.y, P.y,             \
                                fmaf(qc##j.x, P.z, qc##j.y)));
            DD(0) DD(1) DD(2) DD(3) DD(4) DD(5) DD(6) DD(7)
            DD(8) DD(9) DD(10) DD(11) DD(12) DD(13) DD(14) DD(15)
#undef DD
            float e0 = fminf(d0,d1),  e1 = fminf(d2,d3),  e2 = fminf(d4,d5),  e3 = fminf(d6,d7);
            float e4 = fminf(d8,d9),  e5 = fminf(d10,d11), e6 = fminf(d12,d13), e7 = fminf(d14,d15);
            float f0 = fminf(e0,e1), f1 = fminf(e2,e3), f2 = fminf(e4,e5), f3 = fminf(e6,e7);
            float h  = fminf(fminf(f0,f1), fminf(f2,f3));
            m = rotl1(fminf(m, h + s));
            asm volatile("" : "+v"(qa0), "+v"(qa1), "+v"(qa2), "+v"(qa3),
                              "+v"(qa4), "+v"(qa5), "+v"(qa6), "+v"(qa7),
                              "+v"(qa8), "+v"(qa9), "+v"(qa10), "+v"(qa11),
                              "+v"(qa12), "+v"(qa13), "+v"(qa14), "+v"(qa15));
            asm volatile("" : "+v"(qc0), "+v"(qc1), "+v"(qc2), "+v"(qc3),
                              "+v"(qc4), "+v"(qc5), "+v"(qc6), "+v"(qc7),
                              "+v"(qc8), "+v"(qc9), "+v"(qc10), "+v"(qc11),
                              "+v"(qc12), "+v"(qc13), "+v"(qc14), "+v"(qc15));
        }
        rmp[(db*OCG_ + ocg)*NPT_ + pgrp*256 + t] = m;
    }
}

// ---------------------------------------------------------------------------
// fold: per (db, 256-point group): sum 8 winding partials, min 7 rowmin
// partials, block-reduce masked stats -> pstat[db*27+pg].
// ---------------------------------------------------------------------------
__global__ __launch_bounds__(256) void fold_kernel(
        const float* __restrict__ part, const float* __restrict__ rmp,
        float4* __restrict__ pstat) {
    int pg = blockIdx.x % 27, db = blockIdx.x / 27;
    int t = threadIdx.x, n = pg * 256 + t;

    float ws = 0.f;
    #pragma unroll
    for (int g = 0; g < TCG_; ++g) ws += part[(db*TCG_ + g)*NPT_ + n];
    float rv = 3.4e38f;
    #pragma unroll
    for (int g = 0; g < OCG_; ++g) rv = fminf(rv, rmp[(db*OCG_ + g)*NPT_ + n]);

    bool valid = n < N_;
    float d = sqrtf(rv);
    bool msk = valid && (ws >= 0.99f);
    float v_min = valid ? d : 3.4e38f;
    float v_max = msk ? d : -3.4e38f;
    float v_sum = msk ? d : 0.f;
    float v_cnt = msk ? 1.f : 0.f;

    #pragma unroll
    for (int off = 32; off; off >>= 1) {
        v_min = fminf(v_min, __shfl_down(v_min, off, 64));
        v_max = fmaxf(v_max, __shfl_down(v_max, off, 64));
        v_sum += __shfl_down(v_sum, off, 64);
        v_cnt += __shfl_down(v_cnt, off, 64);
    }
    __shared__ float4 sred[4];
    int wid = t >> 6, lane = t & 63;
    if (lane == 0) sred[wid] = make_float4(v_min, v_max, v_sum, v_cnt);
    __syncthreads();
    if (t == 0) {
        float4 a = sred[0], bb = sred[1], c = sred[2], dd = sred[3];
        pstat[db*27 + pg] = make_float4(
            fminf(fminf(a.x, bb.x), fminf(c.x, dd.x)),
            fmaxf(fmaxf(a.y, bb.y), fmaxf(c.y, dd.y)),
            (a.z + bb.z) + (c.z + dd.z),
            (a.w + bb.w) + (c.w + dd.w));
    }
}

// ---------------------------------------------------------------------------
// final: 1 block, wave w reduces db=w's 27 group stats; thread 0 writes [5][B].
// ---------------------------------------------------------------------------
__global__ void final_kernel(const float4* __restrict__ pstat, float* __restrict__ out) {
    int t = threadIdx.x, wid = t >> 6, lane = t & 63;    // wid = db
    float4 v = make_float4(3.4e38f, -3.4e38f, 0.f, 0.f);
    if (lane < 27) v = pstat[wid*27 + lane];
    #pragma unroll
    for (int off = 32; off; off >>= 1) {
        v.x = fminf(v.x, __shfl_down(v.x, off, 64));
        v.y = fmaxf(v.y, __shfl_down(v.y, off, 64));
        v.z += __shfl_down(v.z, off, 64);
        v.w += __shfl_down(v.w, off, 64);
    }
    __shared__ float4 res[4];
    if (lane == 0) res[wid] = v;
    __syncthreads();
    if (t == 0) {
        #pragma unroll
        for (int b = 0; b < B_; ++b) {
            float4 s1 = res[b], s2 = res[2 + b];
            out[0 + b] = s1.x;
            out[2 + b] = (s1.w > 0.f) ? s1.y : 0.f;
            out[4 + b] = (s1.w > 0.f) ? (s1.z / s1.w) : 0.f;
            out[6 + b] = (s2.w > 0.f) ? s2.y : 0.f;
            out[8 + b] = (s2.w > 0.f) ? (s2.z / s2.w) : 0.f;
        }
    }
}

extern "C" void kernel_launch(void* const* d_in, const int* in_sizes, int n_in,
                              void* d_out, int out_size, void* d_ws, size_t ws_size,
                              hipStream_t stream) {
    const float* v1    = (const float*)d_in[0];
    const float* v2    = (const float*)d_in[1];
    const int*   faces = (const int*)d_in[2];

    float4* f4 = (float4*)d_ws;
    float4* pw1   = f4;                         // B*NPT_  = 13824 f4
    float4* pw2   = pw1 + B_ * NPT_;
    float4* st1   = pw2 + B_ * NPT_;            // B*OPP7_ = 14336 f4
    float4* st2   = st1 + B_ * OPP7_;
    float4* pstat = st2 + B_ * OPP7_;           // 108 f4
    float*  tbl1  = (float*)(pstat + 128);      // B*NFP_*20 = 81920 f
    float*  tbl2  = tbl1 + B_ * NFP_ * 20;
    float*  part  = tbl2 + B_ * NFP_ * 20;      // 4*TCG_*NPT_ = 221184 f
    float*  rmp   = part + 4 * TCG_ * NPT_;     // 4*OCG_*NPT_ = 193536 f
                                                // total ~3.3 MB

    float* out = (float*)d_out;

    prep_kernel<<<(B_ * OPP7_ + 255) / 256, 256, 0, stream>>>(
        v1, v2, faces, pw1, pw2, st1, st2, tbl1, tbl2);

    mega_kernel<<<NTILE_, 256, 0, stream>>>(
        pw1, pw2, tbl1, tbl2, st1, st2, part, rmp);

    fold_kernel<<<4 * 27, 256, 0, stream>>>(part, rmp, pstat);

    final_kernel<<<1, 256, 0, stream>>>(pstat, out);
}